// Round 14
// baseline (306.394 us; speedup 1.0000x reference)
//
#include <hip/hip_runtime.h>
#include <hip/hip_bf16.h>

// ---------------------------------------------------------------------------
// GraphSAGE 2-layer: h = relu(mean_agg(x) @ W1l^T + b1 + x @ W1r^T)
//                    out = mean_agg(h) @ W2l^T + b2 + h @ W2r^T
// N=50000, E=800000, C: 128 -> 256 -> 2.
// Round 14: round-12 structure (its 256-thr 128x128 GEMM was fastest), but
// combine2 is eliminated via last-block-combines: each of the 2 col-blocks per
// row-group reduces its wn-halves in LDS, writes one partial set, then
// threadfence + atomicAdd(rcnt); the 2nd arriver sums both sets and writes
// p2/rs directly. 5 dispatches: memset -> scatter_conv -> sort_gather ->
// gemm1_fused -> fin_bucket. Round-13's 1024-thr full-width GEMM regressed
// (2 blk/CU LDS cap, +56% bank conflicts) and is abandoned.
// ---------------------------------------------------------------------------

#define IN_C 128
#define HID_C 256
#define BKT_SHIFT 7
#define BKT_W 128            // dsts per bucket
#define CAP 3072             // bucket slot capacity (mean 2048, sigma 45)

typedef __attribute__((ext_vector_type(8))) short short8;   // 8 bf16 (4 VGPRs)
typedef __attribute__((ext_vector_type(4))) float f32x4;    // MFMA accumulator

static __device__ __forceinline__ unsigned short f2b(float f) {
    __hip_bfloat16 h = __float2bfloat16(f);
    return *(unsigned short*)&h;
}
static __device__ __forceinline__ float b2f(unsigned short u) {
    unsigned v = ((unsigned)u) << 16;
    return *(float*)&v;
}

// ---- fused conversions + direct bucket scatter -----------------------------
// Blocks [0, xblk): xh = bf16(x), fill right half of A. (512 thr)
// Blocks [xblk, xblk+128): Bg = bf16([W1l | W1r]).
// Blocks [xblk+128, ...): scatter 2048 edges/block into fixed bucket slots.
__global__ __launch_bounds__(512) void scatter_conv(
    const float* __restrict__ x, unsigned int* __restrict__ xh,
    unsigned int* __restrict__ Abf,
    const float* __restrict__ w1l, const float* __restrict__ w1r,
    unsigned short* __restrict__ Bg,
    const int* __restrict__ ei, int* __restrict__ bcnt,
    unsigned int* __restrict__ binned,
    int npairs /* N*64 */, int xblk, int E_) {
    __shared__ int hist[512];
    __shared__ int lbase[512];
    const int tid = threadIdx.x;
    if (blockIdx.x < xblk) {
        int t = blockIdx.x * 512 + tid;
        if (t >= npairs) return;
        float2 v = *(const float2*)&x[(size_t)t * 2];
        unsigned int o = ((unsigned)f2b(v.y) << 16) | f2b(v.x);
        xh[t] = o;
        int node = t >> 6, g = t & 63;
        Abf[(size_t)node * 128 + 64 + g] = o;   // A row = 256 bf16 = 128 uints
    } else if (blockIdx.x < xblk + 128) {
        int idx = (blockIdx.x - xblk) * 512 + tid;   // 65536
        int o = idx >> 8, k = idx & 255;
        float f = (k < IN_C) ? w1l[o * IN_C + k] : w1r[o * IN_C + (k - IN_C)];
        Bg[idx] = f2b(f);
    } else {
        const int e0 = (blockIdx.x - xblk - 128) * 2048;
        hist[tid] = 0;
        __syncthreads();
#pragma unroll
        for (int j = 0; j < 4; ++j) {
            int e = e0 + j * 512 + tid;
            if (e < E_) atomicAdd(&hist[ei[E_ + e] >> BKT_SHIFT], 1);
        }
        __syncthreads();
        {
            int c = hist[tid];
            lbase[tid] = c ? tid * CAP + atomicAdd(&bcnt[tid], c) : 0;
            hist[tid] = 0;   // reuse as local cursor
        }
        __syncthreads();
#pragma unroll
        for (int j = 0; j < 4; ++j) {
            int e = e0 + j * 512 + tid;
            if (e < E_) {
                int d = ei[E_ + e];
                int b = d >> BKT_SHIFT;
                int pos = lbase[b] + atomicAdd(&hist[b], 1);
                if (pos < b * CAP + CAP)   // +22 sigma guard, never taken
                    binned[pos] = ((unsigned)ei[e] << BKT_SHIFT) |
                                  (unsigned)(d & (BKT_W - 1));
            }
        }
    }
}

// ---- per-bucket LDS sort + immediate neighbor gather -----------------------

__global__ __launch_bounds__(1024) void sort_gather(
    const unsigned int* __restrict__ binned, const int* __restrict__ bcnt,
    const uint4* __restrict__ xh4, uint4* __restrict__ Abf4,
    int* __restrict__ deg, int n) {
    __shared__ unsigned int ebuf[CAP];        // 12 KB
    __shared__ unsigned short sbuf[CAP];      // 6 KB
    __shared__ int hist[BKT_W];
    __shared__ int offs[BKT_W];
    __shared__ int cur[BKT_W];
    const int tid = threadIdx.x;
    const int lane = tid & 63;
    const int bkt = blockIdx.x;
    const int gbase = bkt * CAP;
    int cnt = bcnt[bkt];
    if (cnt > CAP) cnt = CAP;

    if (tid < BKT_W) hist[tid] = 0;
    for (int i = tid; i < cnt; i += 1024) ebuf[i] = binned[gbase + i];
    __syncthreads();
    for (int i = tid; i < cnt; i += 1024)
        atomicAdd(&hist[ebuf[i] & (BKT_W - 1)], 1);
    __syncthreads();
    if (tid < 64) {   // single-wave scan of 128 counts, 2/lane
        int h0 = hist[lane * 2], h1 = hist[lane * 2 + 1];
        int s = h0 + h1;
        int incl = s;
#pragma unroll
        for (int off = 1; off < 64; off <<= 1) {
            int t = __shfl_up(incl, off);
            if (lane >= off) incl += t;
        }
        int excl = incl - s;
        offs[lane * 2] = excl;          cur[lane * 2] = excl;
        offs[lane * 2 + 1] = excl + h0; cur[lane * 2 + 1] = excl + h0;
    }
    __syncthreads();
    for (int i = tid; i < cnt; i += 1024) {
        unsigned int pk = ebuf[i];
        int pos = atomicAdd(&cur[pk & (BKT_W - 1)], 1);
        sbuf[pos] = (unsigned short)(pk >> BKT_SHIFT);
    }
    if (tid < BKT_W) {
        int node = bkt * BKT_W + tid;
        if (node < n) deg[node] = hist[tid];
    }
    __syncthreads();

    // gather phase: wave wv handles local dsts [wv*8, wv*8+8)
    const int wv = tid >> 6;
    const int ep = lane >> 4;
    const int pos = lane & 15;
    for (int ld = wv * 8; ld < wv * 8 + 8; ++ld) {
        int node = bkt * BKT_W + ld;
        if (node >= n) break;
        int beg = offs[ld], end = offs[ld] + hist[ld];
        float s[8] = {0.f, 0.f, 0.f, 0.f, 0.f, 0.f, 0.f, 0.f};
        for (int e = beg; e < end; e += 8) {
#pragma unroll
            for (int g = 0; g < 2; ++g) {
                int eg = e + g * 4 + ep;
                if (eg < end) {
                    int src = sbuf[eg];
                    uint4 u = xh4[(size_t)src * 16 + pos];
                    s[0] += b2f(u.x & 0xffff); s[1] += b2f(u.x >> 16);
                    s[2] += b2f(u.y & 0xffff); s[3] += b2f(u.y >> 16);
                    s[4] += b2f(u.z & 0xffff); s[5] += b2f(u.z >> 16);
                    s[6] += b2f(u.w & 0xffff); s[7] += b2f(u.w >> 16);
                }
            }
        }
#pragma unroll
        for (int i = 0; i < 8; ++i) {
            s[i] += __shfl_xor(s[i], 16);
            s[i] += __shfl_xor(s[i], 32);
        }
        if (ep == 0) {
            float inv = 1.0f / (float)max(end - beg, 1);
            uint4 o;
            o.x = ((unsigned)f2b(s[1] * inv) << 16) | f2b(s[0] * inv);
            o.y = ((unsigned)f2b(s[3] * inv) << 16) | f2b(s[2] * inv);
            o.z = ((unsigned)f2b(s[5] * inv) << 16) | f2b(s[4] * inv);
            o.w = ((unsigned)f2b(s[7] * inv) << 16) | f2b(s[6] * inv);
            Abf4[(size_t)node * 32 + pos] = o;   // left half of A row
        }
    }
}

// ---- Layer-1 GEMM + fused layer-2 projection (last-block combines) ---------
// Round-12 GEMM shape: 256 thr, 128 rows x 128 cols, grid (391, 2).
// Epilogue: quad butterfly -> 4 KB LDS wn-reduce -> one partial set per
// (rowgroup, by) in gpart -> threadfence + atomicAdd(rcnt); 2nd arriver sums
// both sets and writes p2/rs. No combine2 dispatch.

#define LSTR 72

__global__ __launch_bounds__(256) void gemm1_fused(
    const unsigned short* __restrict__ Abf, const unsigned short* __restrict__ Bg,
    const float* __restrict__ b1, const float* __restrict__ w2l,
    const float* __restrict__ w2r, float* __restrict__ gpart,
    int* __restrict__ rcnt, float2* __restrict__ p2, float2* __restrict__ rs,
    int nn) {
    __shared__ short As[128 * LSTR];
    __shared__ short Bs[128 * LSTR];
    __shared__ float pbuf[8 * 128];     // 4 KB: [ch*2+wn][row]
    __shared__ int last_s;

    const int tid = threadIdx.x;
    const int lane = tid & 63;
    const int wid = tid >> 6;
    const int wm = wid >> 1, wn = wid & 1;
    const int row0 = blockIdx.x * 128;
    const int col0 = blockIdx.y * 128;

    const int srow = tid >> 1;
    const int skc = (tid & 1) * 32;
    int arow = row0 + srow;
    if (arow >= nn) arow = nn - 1;
    const size_t agoff = (size_t)arow * 256 + skc;
    const size_t bgoff = (size_t)(col0 + srow) * 256 + skc;

    f32x4 acc[4][4];
#pragma unroll
    for (int i = 0; i < 4; ++i)
#pragma unroll
        for (int j = 0; j < 4; ++j) acc[i][j] = (f32x4){0.f, 0.f, 0.f, 0.f};

    const int quad = lane >> 4;     // 0..3
    const int l16 = lane & 15;

    for (int k0 = 0; k0 < 256; k0 += 64) {
        const uint4* ga = (const uint4*)(Abf + agoff + k0);
        const uint4* gb = (const uint4*)(Bg + bgoff + k0);
        uint4 va0 = ga[0], va1 = ga[1], va2 = ga[2], va3 = ga[3];
        uint4 vb0 = gb[0], vb1 = gb[1], vb2 = gb[2], vb3 = gb[3];

        __syncthreads();
        uint4* la = (uint4*)&As[srow * LSTR + skc];
        uint4* lb = (uint4*)&Bs[srow * LSTR + skc];
        la[0] = va0; la[1] = va1; la[2] = va2; la[3] = va3;
        lb[0] = vb0; lb[1] = vb1; lb[2] = vb2; lb[3] = vb3;
        __syncthreads();

#pragma unroll
        for (int kb = 0; kb < 2; ++kb) {
            short8 af[4], bf[4];
#pragma unroll
            for (int mt = 0; mt < 4; ++mt)
                af[mt] = *(const short8*)&As[(wm * 64 + mt * 16 + l16) * LSTR + kb * 32 + quad * 8];
#pragma unroll
            for (int nt = 0; nt < 4; ++nt)
                bf[nt] = *(const short8*)&Bs[(wn * 64 + nt * 16 + l16) * LSTR + kb * 32 + quad * 8];
#pragma unroll
            for (int mt = 0; mt < 4; ++mt)
#pragma unroll
                for (int nt = 0; nt < 4; ++nt)
                    acc[mt][nt] = __builtin_amdgcn_mfma_f32_16x16x32_bf16(
                        af[mt], bf[nt], acc[mt][nt], 0, 0, 0);
        }
    }

    // ---- fused projection epilogue ----
    // C/D layout: col = l16, row = quad*4 + reg (m89-verified).
    const int cbase = col0 + wn * 64 + l16;
#pragma unroll
    for (int half = 0; half < 2; ++half) {
        const float* wA = half ? w2r : w2l;          // rows 0,1 of W2{l,r}
        f32x4 part[2][4];
#pragma unroll
        for (int c = 0; c < 2; ++c)
#pragma unroll
            for (int mt = 0; mt < 4; ++mt) part[c][mt] = (f32x4){0.f, 0.f, 0.f, 0.f};
#pragma unroll
        for (int nt = 0; nt < 4; ++nt) {
            const int col = cbase + nt * 16;
            const float bias = b1[col];
            const float w0 = wA[col];
            const float w1 = wA[HID_C + col];
#pragma unroll
            for (int mt = 0; mt < 4; ++mt)
#pragma unroll
                for (int r = 0; r < 4; ++r) {
                    float hv = fmaxf(acc[mt][nt][r] + bias, 0.0f);
                    part[0][mt][r] += hv * w0;
                    part[1][mt][r] += hv * w1;
                }
        }
#pragma unroll
        for (int c = 0; c < 2; ++c)
#pragma unroll
            for (int mt = 0; mt < 4; ++mt)
#pragma unroll
                for (int r = 0; r < 4; ++r)
#pragma unroll
                    for (int m = 1; m < 16; m <<= 1)
                        part[c][mt][r] += __shfl_xor(part[c][mt][r], m);
        // lanes 0..7 of each quad: ch2 = l16&1, mts = l16>>1 (0..3)
        if (l16 < 8) {
            const int ch2 = l16 & 1;
            const int mts = l16 >> 1;
            const int ch = half * 2 + ch2;
#pragma unroll
            for (int r = 0; r < 4; ++r) {
                int lrow = wm * 64 + mts * 16 + quad * 4 + r;   // 0..127
                pbuf[(ch * 2 + wn) * 128 + lrow] = part[ch2][mts][r];
            }
        }
    }
    __syncthreads();

    // wn-reduce -> one partial set per (rowgroup, by); then last-block combine
    if (tid < 128) {
        int node = row0 + tid;
        if (node < nn) {
            float4 v;
            v.x = pbuf[0 * 128 + tid] + pbuf[1 * 128 + tid];
            v.y = pbuf[2 * 128 + tid] + pbuf[3 * 128 + tid];
            v.z = pbuf[4 * 128 + tid] + pbuf[5 * 128 + tid];
            v.w = pbuf[6 * 128 + tid] + pbuf[7 * 128 + tid];
            *(float4*)&gpart[((size_t)node * 2 + blockIdx.y) * 4] = v;
        }
    }
    __threadfence();                       // release partials (device scope)
    if (tid == 0) last_s = atomicAdd(&rcnt[blockIdx.x], 1);
    __syncthreads();
    if (last_s == 1) {                     // this block arrived second
        __threadfence();                   // acquire other block's partials
        if (tid < 128) {
            int node = row0 + tid;
            if (node < nn) {
                float4 a = *(const float4*)&gpart[(size_t)node * 8];
                float4 b = *(const float4*)&gpart[(size_t)node * 8 + 4];
                p2[node] = make_float2(a.x + b.x, a.y + b.y);
                rs[node] = make_float2(a.z + b.z, a.w + b.w);
            }
        }
    }
}

// ---- Layer 2 tail: per-bucket aggregation + finalize -----------------------

__global__ __launch_bounds__(256) void fin_bucket(
    const unsigned int* __restrict__ binned, const int* __restrict__ bcnt,
    const float2* __restrict__ p2, const float2* __restrict__ rs,
    const int* __restrict__ deg, const float* __restrict__ b2,
    float* __restrict__ out, int n) {
    __shared__ float a0[BKT_W];
    __shared__ float a1[BKT_W];
    const int tid = threadIdx.x;
    const int bkt = blockIdx.x;
    const int gbase = bkt * CAP;
    int cnt = bcnt[bkt];
    if (cnt > CAP) cnt = CAP;
    if (tid < BKT_W) { a0[tid] = 0.0f; a1[tid] = 0.0f; }
    __syncthreads();
    for (int i = tid; i < cnt; i += 256) {
        unsigned pk = binned[gbase + i];
        float2 v = p2[pk >> BKT_SHIFT];
        atomicAdd(&a0[pk & (BKT_W - 1)], v.x);
        atomicAdd(&a1[pk & (BKT_W - 1)], v.y);
    }
    __syncthreads();
    if (tid < BKT_W) {
        int node = bkt * BKT_W + tid;
        if (node < n) {
            float inv = 1.0f / (float)max(deg[node], 1);
            float2 self = rs[node];
            out[node * 2 + 0] = a0[tid] * inv + self.x + b2[0];
            out[node * 2 + 1] = a1[tid] * inv + self.y + b2[1];
        }
    }
}

// ---- launch ----------------------------------------------------------------

extern "C" void kernel_launch(void* const* d_in, const int* in_sizes, int n_in,
                              void* d_out, int out_size, void* d_ws, size_t ws_size,
                              hipStream_t stream) {
    const float* x   = (const float*)d_in[0];
    const int*   ei  = (const int*)d_in[1];
    const float* W1l = (const float*)d_in[2];
    const float* b1  = (const float*)d_in[3];
    const float* W1r = (const float*)d_in[4];
    const float* W2l = (const float*)d_in[5];
    const float* b2  = (const float*)d_in[6];
    const float* W2r = (const float*)d_in[7];
    float* out = (float*)d_out;

    const int N_ = in_sizes[0] / IN_C;      // 50000
    const int E_ = in_sizes[1] / 2;         // 800000
    const int nbkt = (N_ + BKT_W - 1) / BKT_W;   // 391

    char* wsb = (char*)d_ws;
    size_t off = 0;
    auto alloc = [&](size_t bytes) {
        void* ptr = wsb + off;
        off += ((bytes + 15) & ~(size_t)15);
        return ptr;
    };
    unsigned short* Abf = (unsigned short*)alloc((size_t)N_ * 256 * 2);  // 25.6 MB
    unsigned int*   xh  = (unsigned int*)alloc((size_t)N_ * 64 * 4);     // 12.8 MB
    unsigned short* Bg  = (unsigned short*)alloc(256 * 256 * 2);         // 128 KB
    float* gpart = (float*)alloc((size_t)N_ * 8 * 4);                    // 1.6 MB
    unsigned int* binned = (unsigned int*)alloc((size_t)(nbkt + 1) * CAP * 4); // 4.8 MB
    int*   ctrs  = (int*)alloc(1024 * 4);   // bcnt[512] + rcnt[512]
    int*   deg   = (int*)alloc((size_t)N_ * 4);
    float2* p2 = (float2*)alloc((size_t)N_ * 2 * 4);
    float2* rs = (float2*)alloc((size_t)N_ * 2 * 4);
    int* bcnt = ctrs;
    int* rcnt = ctrs + 512;
    // total ~46 MB

    const int xblk = (N_ * 64 + 511) / 512;           // 6250
    const int eblk = (E_ + 2047) / 2048;              // 391

    // dispatch 1-2: counter clear + fused conversions/scatter
    hipMemsetAsync(ctrs, 0, 1024 * sizeof(int), stream);
    scatter_conv<<<xblk + 128 + eblk, 512, 0, stream>>>(
        x, xh, (unsigned int*)Abf, W1l, W1r, Bg, ei, bcnt, binned,
        N_ * 64, xblk, E_);

    // dispatch 3: per-bucket sort + layer-1 neighbor gather
    sort_gather<<<nbkt, 1024, 0, stream>>>(binned, bcnt, (const uint4*)xh,
                                           (uint4*)Abf, deg, N_);

    // dispatch 4: MFMA GEMM; projection combined via last-block pattern
    gemm1_fused<<<dim3((N_ + 127) / 128, 2), 256, 0, stream>>>(
        Abf, Bg, b1, W2l, W2r, gpart, rcnt, p2, rs, N_);

    // dispatch 5: per-bucket aggregate + finalize
    fin_bucket<<<nbkt, 256, 0, stream>>>(binned, bcnt, p2, rs, deg, b2, out, N_);
}

// Round 15
// 192.092 us; speedup vs baseline: 1.5950x; 1.5950x over previous
//
#include <hip/hip_runtime.h>
#include <hip/hip_bf16.h>

// ---------------------------------------------------------------------------
// GraphSAGE 2-layer: h = relu(mean_agg(x) @ W1l^T + b1 + x @ W1r^T)
//                    out = mean_agg(h) @ W2l^T + b2 + h @ W2r^T
// N=50000, E=800000, C: 128 -> 256 -> 2.
// Round 15: REVERT to round-12 (193.6 us, best verified).
// Failed experiments (kept for the record):
//  - R13: full-width 1024-thr GEMM w/ in-block projection reduce -> 62 KB LDS
//    caps 2 blk/CU, +56% bank conflicts, GEMM 51 us. Regressed.
//  - R14: last-block-combines w/ __threadfence -> device-scope L2 writeback
//    per block (782x), GEMM 157 us. Regressed hard.
// Pipeline (6 dispatches): memset(bcnt) -> scatter_conv (bf16 convert + W1
// pack + coarse bucket scatter, fused grid) -> sort_gather (per-bucket LDS
// counting sort + immediate neighbor mean-gather) -> gemm1_fused (256-thr
// 128x128 MFMA bf16, layer-2 projection in epilogue, h never materialized)
// -> combine2 -> fin_bucket (per-bucket LDS 2-float aggregation + finalize).
// ---------------------------------------------------------------------------

#define IN_C 128
#define HID_C 256
#define BKT_SHIFT 7
#define BKT_W 128            // dsts per bucket
#define CAP 3072             // bucket slot capacity (mean 2048, sigma 45)

typedef __attribute__((ext_vector_type(8))) short short8;   // 8 bf16 (4 VGPRs)
typedef __attribute__((ext_vector_type(4))) float f32x4;    // MFMA accumulator

static __device__ __forceinline__ unsigned short f2b(float f) {
    __hip_bfloat16 h = __float2bfloat16(f);
    return *(unsigned short*)&h;
}
static __device__ __forceinline__ float b2f(unsigned short u) {
    unsigned v = ((unsigned)u) << 16;
    return *(float*)&v;
}

// ---- fused conversions + direct bucket scatter -----------------------------
// Blocks [0, xblk): xh = bf16(x), fill right half of A. (512 thr)
// Blocks [xblk, xblk+128): Bg = bf16([W1l | W1r]).
// Blocks [xblk+128, ...): scatter 2048 edges/block into fixed bucket slots.
__global__ __launch_bounds__(512) void scatter_conv(
    const float* __restrict__ x, unsigned int* __restrict__ xh,
    unsigned int* __restrict__ Abf,
    const float* __restrict__ w1l, const float* __restrict__ w1r,
    unsigned short* __restrict__ Bg,
    const int* __restrict__ ei, int* __restrict__ bcnt,
    unsigned int* __restrict__ binned,
    int npairs /* N*64 */, int xblk, int E_) {
    __shared__ int hist[512];
    __shared__ int lbase[512];
    const int tid = threadIdx.x;
    if (blockIdx.x < xblk) {
        int t = blockIdx.x * 512 + tid;
        if (t >= npairs) return;
        float2 v = *(const float2*)&x[(size_t)t * 2];
        unsigned int o = ((unsigned)f2b(v.y) << 16) | f2b(v.x);
        xh[t] = o;
        int node = t >> 6, g = t & 63;
        Abf[(size_t)node * 128 + 64 + g] = o;   // A row = 256 bf16 = 128 uints
    } else if (blockIdx.x < xblk + 128) {
        int idx = (blockIdx.x - xblk) * 512 + tid;   // 65536
        int o = idx >> 8, k = idx & 255;
        float f = (k < IN_C) ? w1l[o * IN_C + k] : w1r[o * IN_C + (k - IN_C)];
        Bg[idx] = f2b(f);
    } else {
        const int e0 = (blockIdx.x - xblk - 128) * 2048;
        hist[tid] = 0;
        __syncthreads();
#pragma unroll
        for (int j = 0; j < 4; ++j) {
            int e = e0 + j * 512 + tid;
            if (e < E_) atomicAdd(&hist[ei[E_ + e] >> BKT_SHIFT], 1);
        }
        __syncthreads();
        {
            int c = hist[tid];
            lbase[tid] = c ? tid * CAP + atomicAdd(&bcnt[tid], c) : 0;
            hist[tid] = 0;   // reuse as local cursor
        }
        __syncthreads();
#pragma unroll
        for (int j = 0; j < 4; ++j) {
            int e = e0 + j * 512 + tid;
            if (e < E_) {
                int d = ei[E_ + e];
                int b = d >> BKT_SHIFT;
                int pos = lbase[b] + atomicAdd(&hist[b], 1);
                if (pos < b * CAP + CAP)   // +22 sigma guard, never taken
                    binned[pos] = ((unsigned)ei[e] << BKT_SHIFT) |
                                  (unsigned)(d & (BKT_W - 1));
            }
        }
    }
}

// ---- per-bucket LDS sort + immediate neighbor gather -----------------------

__global__ __launch_bounds__(1024) void sort_gather(
    const unsigned int* __restrict__ binned, const int* __restrict__ bcnt,
    const uint4* __restrict__ xh4, uint4* __restrict__ Abf4,
    int* __restrict__ deg, int n) {
    __shared__ unsigned int ebuf[CAP];        // 12 KB
    __shared__ unsigned short sbuf[CAP];      // 6 KB
    __shared__ int hist[BKT_W];
    __shared__ int offs[BKT_W];
    __shared__ int cur[BKT_W];
    const int tid = threadIdx.x;
    const int lane = tid & 63;
    const int bkt = blockIdx.x;
    const int gbase = bkt * CAP;
    int cnt = bcnt[bkt];
    if (cnt > CAP) cnt = CAP;

    if (tid < BKT_W) hist[tid] = 0;
    for (int i = tid; i < cnt; i += 1024) ebuf[i] = binned[gbase + i];
    __syncthreads();
    for (int i = tid; i < cnt; i += 1024)
        atomicAdd(&hist[ebuf[i] & (BKT_W - 1)], 1);
    __syncthreads();
    if (tid < 64) {   // single-wave scan of 128 counts, 2/lane
        int h0 = hist[lane * 2], h1 = hist[lane * 2 + 1];
        int s = h0 + h1;
        int incl = s;
#pragma unroll
        for (int off = 1; off < 64; off <<= 1) {
            int t = __shfl_up(incl, off);
            if (lane >= off) incl += t;
        }
        int excl = incl - s;
        offs[lane * 2] = excl;          cur[lane * 2] = excl;
        offs[lane * 2 + 1] = excl + h0; cur[lane * 2 + 1] = excl + h0;
    }
    __syncthreads();
    for (int i = tid; i < cnt; i += 1024) {
        unsigned int pk = ebuf[i];
        int pos = atomicAdd(&cur[pk & (BKT_W - 1)], 1);
        sbuf[pos] = (unsigned short)(pk >> BKT_SHIFT);
    }
    if (tid < BKT_W) {
        int node = bkt * BKT_W + tid;
        if (node < n) deg[node] = hist[tid];
    }
    __syncthreads();

    // gather phase: wave wv handles local dsts [wv*8, wv*8+8)
    const int wv = tid >> 6;
    const int ep = lane >> 4;
    const int pos = lane & 15;
    for (int ld = wv * 8; ld < wv * 8 + 8; ++ld) {
        int node = bkt * BKT_W + ld;
        if (node >= n) break;
        int beg = offs[ld], end = offs[ld] + hist[ld];
        float s[8] = {0.f, 0.f, 0.f, 0.f, 0.f, 0.f, 0.f, 0.f};
        for (int e = beg; e < end; e += 8) {
#pragma unroll
            for (int g = 0; g < 2; ++g) {
                int eg = e + g * 4 + ep;
                if (eg < end) {
                    int src = sbuf[eg];
                    uint4 u = xh4[(size_t)src * 16 + pos];
                    s[0] += b2f(u.x & 0xffff); s[1] += b2f(u.x >> 16);
                    s[2] += b2f(u.y & 0xffff); s[3] += b2f(u.y >> 16);
                    s[4] += b2f(u.z & 0xffff); s[5] += b2f(u.z >> 16);
                    s[6] += b2f(u.w & 0xffff); s[7] += b2f(u.w >> 16);
                }
            }
        }
#pragma unroll
        for (int i = 0; i < 8; ++i) {
            s[i] += __shfl_xor(s[i], 16);
            s[i] += __shfl_xor(s[i], 32);
        }
        if (ep == 0) {
            float inv = 1.0f / (float)max(end - beg, 1);
            uint4 o;
            o.x = ((unsigned)f2b(s[1] * inv) << 16) | f2b(s[0] * inv);
            o.y = ((unsigned)f2b(s[3] * inv) << 16) | f2b(s[2] * inv);
            o.z = ((unsigned)f2b(s[5] * inv) << 16) | f2b(s[4] * inv);
            o.w = ((unsigned)f2b(s[7] * inv) << 16) | f2b(s[6] * inv);
            Abf4[(size_t)node * 32 + pos] = o;   // left half of A row
        }
    }
}

// ---- Layer-1 GEMM + fused layer-2 projection -------------------------------
// 256 thr, 128 rows x 128 cols, grid (391, 2). Projection partials ->
// pr_part[row][cby][ch], combined by the separate combine2 kernel.

#define LSTR 72

__global__ __launch_bounds__(256) void gemm1_fused(
    const unsigned short* __restrict__ Abf, const unsigned short* __restrict__ Bg,
    const float* __restrict__ b1, const float* __restrict__ w2l,
    const float* __restrict__ w2r, float* __restrict__ pr_part, int nn) {
    __shared__ short As[128 * LSTR];
    __shared__ short Bs[128 * LSTR];

    const int tid = threadIdx.x;
    const int lane = tid & 63;
    const int wid = tid >> 6;
    const int wm = wid >> 1, wn = wid & 1;
    const int row0 = blockIdx.x * 128;
    const int col0 = blockIdx.y * 128;

    const int srow = tid >> 1;
    const int skc = (tid & 1) * 32;
    int arow = row0 + srow;
    if (arow >= nn) arow = nn - 1;
    const size_t agoff = (size_t)arow * 256 + skc;
    const size_t bgoff = (size_t)(col0 + srow) * 256 + skc;

    f32x4 acc[4][4];
#pragma unroll
    for (int i = 0; i < 4; ++i)
#pragma unroll
        for (int j = 0; j < 4; ++j) acc[i][j] = (f32x4){0.f, 0.f, 0.f, 0.f};

    const int quad = lane >> 4;     // 0..3
    const int l16 = lane & 15;

    for (int k0 = 0; k0 < 256; k0 += 64) {
        const uint4* ga = (const uint4*)(Abf + agoff + k0);
        const uint4* gb = (const uint4*)(Bg + bgoff + k0);
        uint4 va0 = ga[0], va1 = ga[1], va2 = ga[2], va3 = ga[3];
        uint4 vb0 = gb[0], vb1 = gb[1], vb2 = gb[2], vb3 = gb[3];

        __syncthreads();
        uint4* la = (uint4*)&As[srow * LSTR + skc];
        uint4* lb = (uint4*)&Bs[srow * LSTR + skc];
        la[0] = va0; la[1] = va1; la[2] = va2; la[3] = va3;
        lb[0] = vb0; lb[1] = vb1; lb[2] = vb2; lb[3] = vb3;
        __syncthreads();

#pragma unroll
        for (int kb = 0; kb < 2; ++kb) {
            short8 af[4], bf[4];
#pragma unroll
            for (int mt = 0; mt < 4; ++mt)
                af[mt] = *(const short8*)&As[(wm * 64 + mt * 16 + l16) * LSTR + kb * 32 + quad * 8];
#pragma unroll
            for (int nt = 0; nt < 4; ++nt)
                bf[nt] = *(const short8*)&Bs[(wn * 64 + nt * 16 + l16) * LSTR + kb * 32 + quad * 8];
#pragma unroll
            for (int mt = 0; mt < 4; ++mt)
#pragma unroll
                for (int nt = 0; nt < 4; ++nt)
                    acc[mt][nt] = __builtin_amdgcn_mfma_f32_16x16x32_bf16(
                        af[mt], bf[nt], acc[mt][nt], 0, 0, 0);
        }
    }

    // ---- fused projection epilogue (no h materialization) ----
    // C/D layout: col = l16, row = quad*4 + reg (m89-verified).
    const int cbase = col0 + wn * 64 + l16;
    const int cby = blockIdx.y * 2 + wn;   // 0..3 column slot
#pragma unroll
    for (int half = 0; half < 2; ++half) {
        const float* wA = half ? w2r : w2l;          // rows 0,1 of W2{l,r}
        f32x4 part[2][4];
#pragma unroll
        for (int c = 0; c < 2; ++c)
#pragma unroll
            for (int mt = 0; mt < 4; ++mt) part[c][mt] = (f32x4){0.f, 0.f, 0.f, 0.f};
#pragma unroll
        for (int nt = 0; nt < 4; ++nt) {
            const int col = cbase + nt * 16;
            const float bias = b1[col];
            const float w0 = wA[col];
            const float w1 = wA[HID_C + col];
#pragma unroll
            for (int mt = 0; mt < 4; ++mt)
#pragma unroll
                for (int r = 0; r < 4; ++r) {
                    float hv = fmaxf(acc[mt][nt][r] + bias, 0.0f);
                    part[0][mt][r] += hv * w0;
                    part[1][mt][r] += hv * w1;
                }
        }
#pragma unroll
        for (int c = 0; c < 2; ++c)
#pragma unroll
            for (int mt = 0; mt < 4; ++mt)
#pragma unroll
                for (int r = 0; r < 4; ++r)
#pragma unroll
                    for (int m = 1; m < 16; m <<= 1)
                        part[c][mt][r] += __shfl_xor(part[c][mt][r], m);
        if (l16 < 8) {
            const int ch2 = l16 & 1;
            const int mts = l16 >> 1;
#pragma unroll
            for (int r = 0; r < 4; ++r) {
                int row = row0 + wm * 64 + quad * 4 + mts * 16 + r;
                if (row < nn)
                    pr_part[(size_t)row * 16 + cby * 4 + half * 2 + ch2] =
                        part[ch2][mts][r];
            }
        }
    }
}

// ---- Layer 2 tail ----------------------------------------------------------

__global__ void combine2(const float* __restrict__ pr_part,
                         float2* __restrict__ p2, float2* __restrict__ rs, int n) {
    int i = blockIdx.x * 256 + threadIdx.x;
    if (i >= n) return;
    const float4* q = (const float4*)(pr_part + (size_t)i * 16);
    float4 a = q[0], b = q[1], c = q[2], d = q[3];
    p2[i] = make_float2(a.x + b.x + c.x + d.x, a.y + b.y + c.y + d.y);
    rs[i] = make_float2(a.z + b.z + c.z + d.z, a.w + b.w + c.w + d.w);
}

// Per-bucket layer-2 aggregation + finalize (2 LDS ops/edge).
__global__ __launch_bounds__(256) void fin_bucket(
    const unsigned int* __restrict__ binned, const int* __restrict__ bcnt,
    const float2* __restrict__ p2, const float2* __restrict__ rs,
    const int* __restrict__ deg, const float* __restrict__ b2,
    float* __restrict__ out, int n) {
    __shared__ float a0[BKT_W];
    __shared__ float a1[BKT_W];
    const int tid = threadIdx.x;
    const int bkt = blockIdx.x;
    const int gbase = bkt * CAP;
    int cnt = bcnt[bkt];
    if (cnt > CAP) cnt = CAP;
    if (tid < BKT_W) { a0[tid] = 0.0f; a1[tid] = 0.0f; }
    __syncthreads();
    for (int i = tid; i < cnt; i += 256) {
        unsigned pk = binned[gbase + i];
        float2 v = p2[pk >> BKT_SHIFT];
        atomicAdd(&a0[pk & (BKT_W - 1)], v.x);
        atomicAdd(&a1[pk & (BKT_W - 1)], v.y);
    }
    __syncthreads();
    if (tid < BKT_W) {
        int node = bkt * BKT_W + tid;
        if (node < n) {
            float inv = 1.0f / (float)max(deg[node], 1);
            float2 self = rs[node];
            out[node * 2 + 0] = a0[tid] * inv + self.x + b2[0];
            out[node * 2 + 1] = a1[tid] * inv + self.y + b2[1];
        }
    }
}

// ---- launch ----------------------------------------------------------------

extern "C" void kernel_launch(void* const* d_in, const int* in_sizes, int n_in,
                              void* d_out, int out_size, void* d_ws, size_t ws_size,
                              hipStream_t stream) {
    const float* x   = (const float*)d_in[0];
    const int*   ei  = (const int*)d_in[1];
    const float* W1l = (const float*)d_in[2];
    const float* b1  = (const float*)d_in[3];
    const float* W1r = (const float*)d_in[4];
    const float* W2l = (const float*)d_in[5];
    const float* b2  = (const float*)d_in[6];
    const float* W2r = (const float*)d_in[7];
    float* out = (float*)d_out;

    const int N_ = in_sizes[0] / IN_C;      // 50000
    const int E_ = in_sizes[1] / 2;         // 800000
    const int nbkt = (N_ + BKT_W - 1) / BKT_W;   // 391

    char* wsb = (char*)d_ws;
    size_t off = 0;
    auto alloc = [&](size_t bytes) {
        void* ptr = wsb + off;
        off += ((bytes + 15) & ~(size_t)15);
        return ptr;
    };
    unsigned short* Abf = (unsigned short*)alloc((size_t)N_ * 256 * 2);  // 25.6 MB
    unsigned int*   xh  = (unsigned int*)alloc((size_t)N_ * 64 * 4);     // 12.8 MB
    unsigned short* Bg  = (unsigned short*)alloc(256 * 256 * 2);         // 128 KB
    float* pr_part = (float*)alloc((size_t)N_ * 16 * 4);                 // 3.2 MB
    unsigned int* binned = (unsigned int*)alloc((size_t)(nbkt + 1) * CAP * 4); // 4.8 MB
    int*   bcnt   = (int*)alloc(512 * 4);
    int*   deg    = (int*)alloc((size_t)N_ * 4);
    float2* p2 = (float2*)alloc((size_t)N_ * 2 * 4);
    float2* rs = (float2*)alloc((size_t)N_ * 2 * 4);
    // total ~47 MB

    const int xblk = (N_ * 64 + 511) / 512;           // 6250
    const int eblk = (E_ + 2047) / 2048;              // 391

    // dispatch 1-2: cursor clear + fused conversions/scatter
    hipMemsetAsync(bcnt, 0, 512 * sizeof(int), stream);
    scatter_conv<<<xblk + 128 + eblk, 512, 0, stream>>>(
        x, xh, (unsigned int*)Abf, W1l, W1r, Bg, ei, bcnt, binned,
        N_ * 64, xblk, E_);

    // dispatch 3: per-bucket sort + layer-1 neighbor gather
    sort_gather<<<nbkt, 1024, 0, stream>>>(binned, bcnt, (const uint4*)xh,
                                           (uint4*)Abf, deg, N_);

    // dispatch 4: MFMA GEMM with fused layer-2 projection
    gemm1_fused<<<dim3((N_ + 127) / 128, 2), 256, 0, stream>>>(
        Abf, Bg, b1, W2l, W2r, pr_part, N_);

    // dispatch 5-6: combine partials, per-bucket aggregate + finalize
    combine2<<<(N_ + 255) / 256, 256, 0, stream>>>(pr_part, p2, rs, N_);
    fin_bucket<<<nbkt, 256, 0, stream>>>(binned, bcnt, p2, rs, deg, b2, out, N_);
}